// Round 17
// baseline (217.426 us; speedup 1.0000x reference)
//
#include <hip/hip_runtime.h>
#include <hip/hip_bf16.h>
#include <math.h>

#define TPB 256

typedef __attribute__((ext_vector_type(8))) short short8;
typedef __attribute__((ext_vector_type(4))) float f32x4;
typedef unsigned short u16;

__device__ __forceinline__ f32x4 MFMA(short8 a, short8 b, f32x4 c) {
    return __builtin_amdgcn_mfma_f32_16x16x32_bf16(a, b, c, 0, 0, 0);
}
// manual RNE cvt (prep_w only; runs once)
__device__ __forceinline__ u16 f2bf(float f) {
    unsigned int u = __builtin_bit_cast(unsigned int, f);
    u += 0x7FFFu + ((u >> 16) & 1u);
    return (u16)(u >> 16);
}
// hot-path cvt: hardware v_cvt. hi rounding mode irrelevant: lo self-corrects.
__device__ __forceinline__ u16 f2bf_hw(float f) {
    __hip_bfloat16 b = __float2bfloat16(f);
    return __builtin_bit_cast(u16, b);
}
__device__ __forceinline__ float bf2f(u16 h) {
    unsigned int u = ((unsigned int)h) << 16;
    return __builtin_bit_cast(float, u);
}

// ============ weight-fragment pre-kernel ============
// ws layout (short8 slots): entry = slot>>6, lane = slot&63.
//  K2:  ent [0,6)    = s*2+hl                 (s<3)
//  K3:  ent [6,16)   = 6  + s*2+hl            (s<5)
//  K4:  ent [16,26)  = 16 + s*2+hl
//  K5:  ent [26,36)  = 26 + s*2+hl
//  K6:  ent [36,88)  = 36 + s*4+hl*2+nh       (s<13, nh = cout half)
//  K1:  ent [88,96)  = 88 + s*2+hl            (s<4; k' = (c*5+kh)*8+kw, kw 5..7 pad)
extern "C" __global__ void prep_w(const float* __restrict__ K1, const float* __restrict__ K2,
                                  const float* __restrict__ K3, const float* __restrict__ K4,
                                  const float* __restrict__ K5, const float* __restrict__ K6,
                                  short8* __restrict__ W)
{
    const int slot = blockIdx.x * blockDim.x + threadIdx.x;
    if (slot >= 6144) return;
    const int lane = slot & 63;
    const int ent  = slot >> 6;
    const int o    = lane & 15;
    const int lhi  = lane >> 4;
    float w[8];
    int hl;
    if (ent < 6) {                       // K2: k' = tap*8 + c, tap = s*4+lhi
        const int s = ent >> 1; hl = ent & 1;
        const int t = s * 4 + lhi;
#pragma unroll
        for (int j = 0; j < 8; j++)
            w[j] = (t < 9) ? K2[(j * 9 + t) * 16 + o] : 0.f;
    } else if (ent < 36) {               // K3/4/5: k' = tap*16 + c
        const int e  = ent - 6;
        const float* Kg = (e < 10) ? K3 : (e < 20) ? K4 : K5;
        const int el = e % 10;
        const int s  = el >> 1; hl = el & 1;
        const int chalf = (lhi & 1) * 8;
        const int t = 2 * s + (lhi >> 1);
#pragma unroll
        for (int j = 0; j < 8; j++)
            w[j] = (t < 9) ? Kg[((chalf + j) * 9 + t) * 16 + o] : 0.f;
    } else if (ent < 88) {               // K6: k' = tap*16 + c, tap<25
        const int e = ent - 36;
        const int s = e >> 2; hl = (e >> 1) & 1;
        const int nh = e & 1;
        const int chalf = (lhi & 1) * 8;
        const int t  = 2 * s + (lhi >> 1);
        const int oo = nh * 16 + o;
#pragma unroll
        for (int j = 0; j < 8; j++)
            w[j] = (t < 25) ? K6[((chalf + j) * 25 + t) * 32 + oo] : 0.f;
    } else {                             // K1: group g = s*4+lhi = c*5+kh (g=15 pad), j=kw (5..7 pad)
        const int e = ent - 88;
        const int s = e >> 1; hl = e & 1;
        const int g  = s * 4 + lhi;
        const int gc = g > 14 ? 14 : g;
        const int c  = (gc * 52) >> 8;   // gc/5
        const int kh = gc - 5 * c;
#pragma unroll
        for (int j = 0; j < 8; j++)
            w[j] = (g < 15 && o < 8 && j < 5) ? K1[(c * 25 + kh * 5 + j) * 8 + o] : 0.f;
    }
    short8 v;
#pragma unroll
    for (int j = 0; j < 8; j++) {
        const u16 h = f2bf(w[j]);
        v[j] = hl ? (short)f2bf(w[j] - bf2f(h)) : (short)h;
    }
    W[slot] = v;
}

// ============ conv helpers (half-channel-plane LDS layout, 15x15 pad) ============
// 16-ch tensor @ base (shorts): hi half0 [0,1800), hi half1 [1800,3600),
//                               lo half0 [3600,5400), lo half1 [5400,7200)
// row stride 15 px, pixel stride 8 shorts = 16 B. Plane stride 1800 shorts is
// bank-proven (r15: 1680 stride raised conflicts 17.6M->26.2M).
// 4-wave dispatch: m0=(wave+rot)&3 -> tiles m0, m0+4 (and 8 when m0==0).
// DUAL-TILE interleave: tiles m0 and m0+4 share B[s] per step and run two
// INDEPENDENT acc chains -> MFMA dependency stalls ~halve. B loaded per-step
// (not preloaded arrays) so register residency stays under the 64-VGPR cliff
// (r13: +1 acc on the same-tile chain went 48->68 and halved occupancy).

__device__ __forceinline__ void conv8(const u16* __restrict__ s0,   // 8-ch src: hi [0,1800), lo +3600
                                      u16* __restrict__ d0,
                                      const short8* __restrict__ Wt,
                                      int wave, int lane, int rot)
{
    const int o   = lane & 15;
    const int lhi = lane >> 4;
    const u16* sl = s0 + 3600;
    const int r0 = lane & 15;

    auto epi = [&](int m, const f32x4& acc) {
        const int p0 = m * 16 + lhi * 4;
#pragma unroll
        for (int r = 0; r < 4; r++) {
            const int pp = p0 + r;
            const int ii = (pp * 683) >> 13;
            const int jj = pp - 12 * ii;
            const float v = fmaxf(acc[r], 0.f);
            const u16 h = f2bf_hw(v);
            const int px2 = (ii + 1) * 15 + (jj + 1);
            const int da  = (o >> 3) * 1800 + px2 * 8 + (o & 7);
            d0[da]        = h;
            d0[da + 3600] = f2bf_hw(v - bf2f(h));
        }
    };

    const int m0 = (wave + rot) & 3;
    {   // dual: tiles m0 and m0+4, interleaved chains
        const int pa = m0 * 16 + r0;
        const int ipa = (pa * 683) >> 13, jpa = pa - 12 * ipa;
        const int pb = (m0 + 4) * 16 + r0;
        const int ipb = (pb * 683) >> 13, jpb = pb - 12 * ipb;
        f32x4 accA = {0.f, 0.f, 0.f, 0.f};
        f32x4 accB = {0.f, 0.f, 0.f, 0.f};
#pragma unroll
        for (int s = 0; s < 3; s++) {
            const short8 Bh = Wt[(s * 2 + 0) * 64 + lane];
            const short8 Bl = Wt[(s * 2 + 1) * 64 + lane];
            const int t  = s * 4 + lhi;
            const int tt = t > 8 ? 8 : t;
            const int kh = (tt * 11) >> 5;       // tt/3
            const int kw = tt - 3 * kh;
            const int pxa = (ipa + kh) * 15 + (jpa + kw);
            const int pxb = (ipb + kh) * 15 + (jpb + kw);
            const short8 A1h = *(const short8*)(s0 + pxa * 8);
            const short8 A1l = *(const short8*)(sl + pxa * 8);
            const short8 A2h = *(const short8*)(s0 + pxb * 8);
            const short8 A2l = *(const short8*)(sl + pxb * 8);
            accA = MFMA(A1h, Bh, accA);  accB = MFMA(A2h, Bh, accB);
            accA = MFMA(A1l, Bh, accA);  accB = MFMA(A2l, Bh, accB);
            accA = MFMA(A1h, Bl, accA);  accB = MFMA(A2h, Bl, accB);
        }
        epi(m0, accA);
        epi(m0 + 4, accB);
    }
    if (m0 == 0) {   // tile 8, single chain
        const int p  = 128 + r0;
        const int ip = (p * 683) >> 13, jp = p - 12 * ip;
        f32x4 acc = {0.f, 0.f, 0.f, 0.f};
#pragma unroll
        for (int s = 0; s < 3; s++) {
            const short8 Bh = Wt[(s * 2 + 0) * 64 + lane];
            const short8 Bl = Wt[(s * 2 + 1) * 64 + lane];
            const int t  = s * 4 + lhi;
            const int tt = t > 8 ? 8 : t;
            const int kh = (tt * 11) >> 5;
            const int kw = tt - 3 * kh;
            const int px = (ip + kh) * 15 + (jp + kw);
            const short8 Ahi = *(const short8*)(s0 + px * 8);
            const short8 Alo = *(const short8*)(sl + px * 8);
            acc = MFMA(Ahi, Bh, acc);
            acc = MFMA(Alo, Bh, acc);
            acc = MFMA(Ahi, Bl, acc);
        }
        epi(8, acc);
    }
}

__device__ __forceinline__ void conv16(const u16* __restrict__ s0,
                                       u16* __restrict__ d0,
                                       const short8* __restrict__ Wt,
                                       int wave, int lane, int rot)
{
    const int o    = lane & 15;
    const int lhi  = lane >> 4;
    const int hsel = lhi & 1;
    const int tsel = lhi >> 1;
    const u16* sh = s0 + hsel * 1800;
    const u16* sl = sh + 3600;
    const int r0 = lane & 15;

    auto epi = [&](int m, const f32x4& acc) {
        const int p0 = m * 16 + lhi * 4;
#pragma unroll
        for (int r = 0; r < 4; r++) {
            const int pp = p0 + r;
            const int ii = (pp * 683) >> 13;
            const int jj = pp - 12 * ii;
            const float v = fmaxf(acc[r], 0.f);
            const u16 h = f2bf_hw(v);
            const int px2 = (ii + 1) * 15 + (jj + 1);
            const int da  = (o >> 3) * 1800 + px2 * 8 + (o & 7);
            d0[da]        = h;
            d0[da + 3600] = f2bf_hw(v - bf2f(h));
        }
    };

    const int m0 = (wave + rot) & 3;
    {   // dual: tiles m0 and m0+4, interleaved chains
        const int pa = m0 * 16 + r0;
        const int ipa = (pa * 683) >> 13, jpa = pa - 12 * ipa;
        const int pb = (m0 + 4) * 16 + r0;
        const int ipb = (pb * 683) >> 13, jpb = pb - 12 * ipb;
        f32x4 accA = {0.f, 0.f, 0.f, 0.f};
        f32x4 accB = {0.f, 0.f, 0.f, 0.f};
#pragma unroll
        for (int s = 0; s < 5; s++) {
            const short8 Bh = Wt[(s * 2 + 0) * 64 + lane];
            const short8 Bl = Wt[(s * 2 + 1) * 64 + lane];
            const int t  = 2 * s + tsel;
            const int tt = t > 8 ? 8 : t;
            const int kh = (tt * 11) >> 5;
            const int kw = tt - 3 * kh;
            const int pxa = (ipa + kh) * 15 + (jpa + kw);
            const int pxb = (ipb + kh) * 15 + (jpb + kw);
            const short8 A1h = *(const short8*)(sh + pxa * 8);
            const short8 A1l = *(const short8*)(sl + pxa * 8);
            const short8 A2h = *(const short8*)(sh + pxb * 8);
            const short8 A2l = *(const short8*)(sl + pxb * 8);
            accA = MFMA(A1h, Bh, accA);  accB = MFMA(A2h, Bh, accB);
            accA = MFMA(A1l, Bh, accA);  accB = MFMA(A2l, Bh, accB);
            accA = MFMA(A1h, Bl, accA);  accB = MFMA(A2h, Bl, accB);
        }
        epi(m0, accA);
        epi(m0 + 4, accB);
    }
    if (m0 == 0) {   // tile 8, single chain
        const int p  = 128 + r0;
        const int ip = (p * 683) >> 13, jp = p - 12 * ip;
        f32x4 acc = {0.f, 0.f, 0.f, 0.f};
#pragma unroll
        for (int s = 0; s < 5; s++) {
            const short8 Bh = Wt[(s * 2 + 0) * 64 + lane];
            const short8 Bl = Wt[(s * 2 + 1) * 64 + lane];
            const int t  = 2 * s + tsel;
            const int tt = t > 8 ? 8 : t;
            const int kh = (tt * 11) >> 5;
            const int kw = tt - 3 * kh;
            const int px = (ip + kh) * 15 + (jp + kw);
            const short8 Ahi = *(const short8*)(sh + px * 8);
            const short8 Alo = *(const short8*)(sl + px * 8);
            acc = MFMA(Ahi, Bh, acc);
            acc = MFMA(Alo, Bh, acc);
            acc = MFMA(Ahi, Bl, acc);
        }
        epi(8, acc);
    }
}

// ============ main fused kernel ============
// r14 structure (TPB=256, 15x15 planes, 29184 B LDS -> 5 blocks/CU, in-phase
// zeros) + dual-tile interleaved MFMA chains with per-step B loads.
// Hard-won constraints: min-waves launch_bounds pins spill (r3/r8); VGPR>64
// halves occupancy (r13); TPB!=256 loses (r8/r9/r12); plane stride 1800 is
// bank-optimal (r11/r15); setprio null here (r16).
extern "C" __global__ void __launch_bounds__(TPB)
cnn_fused(const float* __restrict__ xg,
          const float* __restrict__ Wfc, const float* __restrict__ bfc,
          const short8* __restrict__ W, float* __restrict__ out)
{
    // byte map:
    //  A [0,14400)      : 16-ch tensor (4 planes of 1800 shorts)
    //  B [14400,28800)  : image bf16 [3][30][32] hi/lo first; then 16-ch tensor;
    //                     finally sF f32[1152]. Ring re-zeroed inside L2 phase.
    //  sLog [28800,28864)
    __shared__ __align__(16) unsigned char smem[28864];
    u16*   const Ah   = (u16*)smem;
    u16*   const Bh   = (u16*)(smem + 14400);
    u16*   const Sh   = (u16*)(smem + 14400);    // image: hi 2880 shorts, lo +2880
    float* const sF   = (float*)(smem + 14400);
    float* const sLog = (float*)(smem + 28800);
    uint4* const z4   = (uint4*)smem;
    const uint4 Z = {0u, 0u, 0u, 0u};

    const int tid  = threadIdx.x;
    const int lane = tid & 63;
    const int wave = tid >> 6;
    const int img  = blockIdx.x;

    // full clear (1804 x 16B): A's pad rings + image pad ring stay zero
    for (int i = tid; i < 1804; i += TPB) z4[i] = Z;
    __syncthreads();

    // stage image as bf16 hi/lo planar [3][30][32] into B, interior rows/cols 1..28
    const float4* xi4 = (const float4*)(xg + (size_t)img * 2352);
    for (int i4 = tid; i4 < 588; i4 += TPB) {
        const float4 v = xi4[i4];
        const int c = i4 / 196;
        const int rem = i4 - c * 196;
        const int r = rem / 7;
        const int q = rem - r * 7;
        const int ad = c * 960 + (r + 1) * 32 + q * 4 + 1;
        const float vv[4] = {v.x, v.y, v.z, v.w};
#pragma unroll
        for (int e = 0; e < 4; e++) {
            const u16 h = f2bf_hw(vv[e]);
            Sh[ad + e]        = h;
            Sh[ad + e + 2880] = f2bf_hw(vv[e] - bf2f(h));
        }
    }
    __syncthreads();

    // ---- L1: 5x5 s2 p1, 3->8, 13x13 full, ReLU. MFMA split bf16. B(img) -> A(8ch)
    // Dual-tile interleave for m=wave, wave+4; single for m=wave+8 (wave<3).
    {
        const short8* Wt1 = W + 5632;            // ent 88
        const int o   = lane & 15;
        const int lhi = lane >> 4;
        const u16* slo = Sh + 2880;

        auto epi1 = [&](int m, const f32x4& acc) {
#pragma unroll
            for (int r = 0; r < 4; r++) {
                const int pp = m * 16 + lhi * 4 + r;
                if (pp < 169 && o < 8) {
                    const int ii = (pp * 316) >> 12;
                    const int jj = pp - 13 * ii;
                    const float v = fmaxf(acc[r], 0.f);
                    const u16 h = f2bf_hw(v);
                    const int da = ((ii + 1) * 15 + (jj + 1)) * 8 + o;
                    Ah[da]        = h;
                    Ah[da + 3600] = f2bf_hw(v - bf2f(h));
                }
            }
        };

        {   // dual: m = wave, wave+4
            const int pa = wave * 16 + o;
            const int ia = (pa * 316) >> 12, ja = pa - 13 * ia;
            const int pbm = (wave + 4) * 16 + o;
            const int pb = pbm > 168 ? 168 : pbm;
            const int ib = (pb * 316) >> 12, jb = pb - 13 * ib;
            f32x4 accA = {0.f, 0.f, 0.f, 0.f};
            f32x4 accB = {0.f, 0.f, 0.f, 0.f};
#pragma unroll
            for (int s = 0; s < 4; s++) {
                const short8 B1h = Wt1[(s * 2 + 0) * 64 + lane];
                const short8 B1l = Wt1[(s * 2 + 1) * 64 + lane];
                const int g  = s * 4 + lhi;
                const int gc = g > 14 ? 14 : g;
                const int c  = (gc * 52) >> 8;   // gc/5
                const int kh = gc - 5 * c;
                const int ada = c * 960 + (2 * ia + kh) * 32 + 2 * ja;
                const int adb = c * 960 + (2 * ib + kh) * 32 + 2 * jb;
                const short8 A1h = *(const short8*)(Sh + ada);
                const short8 A1l = *(const short8*)(slo + ada);
                const short8 A2h = *(const short8*)(Sh + adb);
                const short8 A2l = *(const short8*)(slo + adb);
                accA = MFMA(A1h, B1h, accA);  accB = MFMA(A2h, B1h, accB);
                accA = MFMA(A1l, B1h, accA);  accB = MFMA(A2l, B1h, accB);
                accA = MFMA(A1h, B1l, accA);  accB = MFMA(A2h, B1l, accB);
            }
            epi1(wave, accA);
            epi1(wave + 4, accB);
        }
        if (wave < 3) {   // single: m = wave+8 (tiles 8..10)
            const int m  = wave + 8;
            const int p  = m * 16 + o;
            const int pc = p > 168 ? 168 : p;
            const int i = (pc * 316) >> 12;
            const int j = pc - 13 * i;
            f32x4 acc = {0.f, 0.f, 0.f, 0.f};
#pragma unroll
            for (int s = 0; s < 4; s++) {
                const short8 B1h = Wt1[(s * 2 + 0) * 64 + lane];
                const short8 B1l = Wt1[(s * 2 + 1) * 64 + lane];
                const int g  = s * 4 + lhi;
                const int gc = g > 14 ? 14 : g;
                const int c  = (gc * 52) >> 8;
                const int kh = gc - 5 * c;
                const int ad = c * 960 + (2 * i + kh) * 32 + 2 * j;
                const short8 Ahi = *(const short8*)(Sh + ad);
                const short8 Alo = *(const short8*)(slo + ad);
                acc = MFMA(Ahi, B1h, acc);
                acc = MFMA(Alo, B1h, acc);
                acc = MFMA(Ahi, B1l, acc);
            }
            epi1(m, acc);
        }
    }
    __syncthreads();

    // ---- L2 phase: conv8 A8 -> B16, plus B read-extent ring zero (rows/cols
    // 0 and 13 of each plane; stale image bytes live there). Ring is disjoint
    // from L2's interior writes; L2 reads only A -> race-free in-phase.
    conv8(Ah, Bh, W, wave, lane, 0);
    if (tid < 208) {
        const int pl = tid / 52, e = tid - pl * 52;
        const int px = (e < 14) ? e
                     : (e < 28) ? 195 + (e - 14)
                     : (e < 40) ? (e - 27) * 15
                                : (e - 39) * 15 + 13;
        z4[900 + pl * 225 + px] = Z;
    }
    __syncthreads();

    // ---- L3 phase: conv16 B -> A, plus strip-zero of A px row/col 13 (holds
    // stale L1 row/col 12; reference has L3's truncated zeros there). Disjoint
    // from L3's interior writes; L3 reads only B. (r11/r14: absmax -> 0.0)
    conv16(Bh, Ah, W + 384, wave, lane, 1);
    if (tid < 108) {
        const int pl = tid / 27, e = tid - pl * 27;
        const int px = (e < 14) ? 195 + e : (e - 14) * 15 + 13;
        z4[pl * 225 + px] = Z;
    }
    __syncthreads();

    conv16(Ah, Bh, W + 1024, wave, lane, 2);       // L4: A -> B (B px13 ring still zero)
    __syncthreads();
    conv16(Bh, Ah, W + 1664, wave, lane, 3);       // L5: B -> A (A px13 strip still zero)
    __syncthreads();

    // ---- L6 phase: conv A -> sF [32][6][6] planar, plus zero of sF's
    // complement slots (row 5 + col 5 of each 6x6 map, 11 slots x 32 ch).
    // Complement is disjoint from L6's interior writes; L6 reads only A.
    for (int i = tid; i < 352; i += TPB) {
        const int o = i / 11, k = i - o * 11;
        const int slot = (k < 6) ? o * 36 + 30 + k : o * 36 + (k - 6) * 6 + 5;
        sF[slot] = 0.f;
    }
    if (wave < 4) {
        const short8* Wt6 = W + 2304;
        const int mt   = wave >> 1;
        const int nh   = wave & 1;
        const int lhi  = lane >> 4;
        const int hsel = lhi & 1;
        const int tsel = lhi >> 1;
        const int o    = nh * 16 + (lane & 15);
        const int pr = mt * 16 + (lane & 15);
        const int pe = pr < 25 ? pr : 0;
        const int ia = (pe * 52) >> 8;            // pe/5
        const int ja = pe - 5 * ia;
        const u16* sh = Ah + hsel * 1800;
        const u16* sl = sh + 3600;
        f32x4 acc = {0.f, 0.f, 0.f, 0.f};
#pragma unroll 4
        for (int s = 0; s < 13; s++) {
            const int t  = 2 * s + tsel;
            const int tt = t > 24 ? 24 : t;
            const int kh = (tt * 52) >> 8;        // tt/5
            const int kw = tt - 5 * kh;
            const int px = (2 * ia + kh) * 15 + (2 * ja + kw);
            const short8 Ahi = *(const short8*)(sh + px * 8);
            const short8 Alo = *(const short8*)(sl + px * 8);
            const short8 Bh2 = Wt6[((s * 2 + 0) * 2 + nh) * 64 + lane];
            const short8 Bl2 = Wt6[((s * 2 + 1) * 2 + nh) * 64 + lane];
            acc = MFMA(Ahi, Bh2, acc);
            acc = MFMA(Alo, Bh2, acc);
            acc = MFMA(Ahi, Bl2, acc);
        }
        const int p0 = mt * 16 + lhi * 4;
#pragma unroll
        for (int r = 0; r < 4; r++) {
            const int pp = p0 + r;
            if (pp < 25) {
                const int ii = (pp * 52) >> 8;
                const int jj = pp - 5 * ii;
                sF[o * 36 + ii * 6 + jj] = acc[r];
            }
        }
    }
    __syncthreads();

    // ---- FC: logits[c] = sF . Wfc[c] + bfc[c]
    if (tid < 160) {
        const int c = tid >> 4;
        const int l = tid & 15;
        const float4* fv = (const float4*)(sF + l * 72);
        const float4* wv = (const float4*)(Wfc + c * 1152 + l * 72);
        float p = 0.f;
#pragma unroll
        for (int m = 0; m < 18; m++) {
            const float4 a = fv[m];
            const float4 b = wv[m];
            p = fmaf(a.x, b.x, p);
            p = fmaf(a.y, b.y, p);
            p = fmaf(a.z, b.z, p);
            p = fmaf(a.w, b.w, p);
        }
        p += __shfl_down(p, 8, 16);
        p += __shfl_down(p, 4, 16);
        p += __shfl_down(p, 2, 16);
        p += __shfl_down(p, 1, 16);
        if (l == 0) sLog[c] = p + bfc[c];
    }
    __syncthreads();

    // ---- softmax
    if (tid < 10) {
        float mx = sLog[0];
#pragma unroll
        for (int k = 1; k < 10; k++) mx = fmaxf(mx, sLog[k]);
        float s = 0.f;
#pragma unroll
        for (int k = 0; k < 10; k++) s += expf(sLog[k] - mx);
        out[(size_t)img * 10 + tid] = expf(sLog[tid] - mx) / s;
    }
}

extern "C" void kernel_launch(void* const* d_in, const int* in_sizes, int n_in,
                              void* d_out, int out_size, void* d_ws, size_t ws_size,
                              hipStream_t stream) {
    const float* x   = (const float*)d_in[0];
    const float* K1  = (const float*)d_in[1];
    const float* K2  = (const float*)d_in[2];
    const float* K3  = (const float*)d_in[3];
    const float* K4  = (const float*)d_in[4];
    const float* K5  = (const float*)d_in[5];
    const float* K6  = (const float*)d_in[6];
    const float* Wfc = (const float*)d_in[7];
    const float* bfc = (const float*)d_in[8];
    float* out = (float*)d_out;
    short8* W = (short8*)d_ws;

    prep_w<<<24, 256, 0, stream>>>(K1, K2, K3, K4, K5, K6, W);

    const int B = in_sizes[0] / 2352;   // 8192
    cnn_fused<<<B, TPB, 0, stream>>>(x, Wfc, bfc, W, out);
}

// Round 18
// 203.436 us; speedup vs baseline: 1.0688x; 1.0688x over previous
//
#include <hip/hip_runtime.h>
#include <hip/hip_bf16.h>
#include <math.h>

#define TPB 256

typedef __attribute__((ext_vector_type(8))) short short8;
typedef __attribute__((ext_vector_type(4))) float f32x4;
typedef unsigned short u16;

__device__ __forceinline__ f32x4 MFMA(short8 a, short8 b, f32x4 c) {
    return __builtin_amdgcn_mfma_f32_16x16x32_bf16(a, b, c, 0, 0, 0);
}
// manual RNE cvt (prep_w only; runs once)
__device__ __forceinline__ u16 f2bf(float f) {
    unsigned int u = __builtin_bit_cast(unsigned int, f);
    u += 0x7FFFu + ((u >> 16) & 1u);
    return (u16)(u >> 16);
}
// hot-path cvt: hardware v_cvt. hi rounding mode irrelevant: lo self-corrects.
__device__ __forceinline__ u16 f2bf_hw(float f) {
    __hip_bfloat16 b = __float2bfloat16(f);
    return __builtin_bit_cast(u16, b);
}
__device__ __forceinline__ float bf2f(u16 h) {
    unsigned int u = ((unsigned int)h) << 16;
    return __builtin_bit_cast(float, u);
}

// ============ weight-fragment pre-kernel ============
// ws layout (short8 slots): entry = slot>>6, lane = slot&63.
//  K2:  ent [0,6)    = s*2+hl                 (s<3)
//  K3:  ent [6,16)   = 6  + s*2+hl            (s<5)
//  K4:  ent [16,26)  = 16 + s*2+hl
//  K5:  ent [26,36)  = 26 + s*2+hl
//  K6:  ent [36,88)  = 36 + s*4+hl*2+nh       (s<13, nh = cout half)
//  K1:  ent [88,96)  = 88 + s*2+hl            (s<4; k' = (c*5+kh)*8+kw, kw 5..7 pad)
extern "C" __global__ void prep_w(const float* __restrict__ K1, const float* __restrict__ K2,
                                  const float* __restrict__ K3, const float* __restrict__ K4,
                                  const float* __restrict__ K5, const float* __restrict__ K6,
                                  short8* __restrict__ W)
{
    const int slot = blockIdx.x * blockDim.x + threadIdx.x;
    if (slot >= 6144) return;
    const int lane = slot & 63;
    const int ent  = slot >> 6;
    const int o    = lane & 15;
    const int lhi  = lane >> 4;
    float w[8];
    int hl;
    if (ent < 6) {                       // K2: k' = tap*8 + c, tap = s*4+lhi
        const int s = ent >> 1; hl = ent & 1;
        const int t = s * 4 + lhi;
#pragma unroll
        for (int j = 0; j < 8; j++)
            w[j] = (t < 9) ? K2[(j * 9 + t) * 16 + o] : 0.f;
    } else if (ent < 36) {               // K3/4/5: k' = tap*16 + c
        const int e  = ent - 6;
        const float* Kg = (e < 10) ? K3 : (e < 20) ? K4 : K5;
        const int el = e % 10;
        const int s  = el >> 1; hl = el & 1;
        const int chalf = (lhi & 1) * 8;
        const int t = 2 * s + (lhi >> 1);
#pragma unroll
        for (int j = 0; j < 8; j++)
            w[j] = (t < 9) ? Kg[((chalf + j) * 9 + t) * 16 + o] : 0.f;
    } else if (ent < 88) {               // K6: k' = tap*16 + c, tap<25
        const int e = ent - 36;
        const int s = e >> 2; hl = (e >> 1) & 1;
        const int nh = e & 1;
        const int chalf = (lhi & 1) * 8;
        const int t  = 2 * s + (lhi >> 1);
        const int oo = nh * 16 + o;
#pragma unroll
        for (int j = 0; j < 8; j++)
            w[j] = (t < 25) ? K6[((chalf + j) * 25 + t) * 32 + oo] : 0.f;
    } else {                             // K1: group g = s*4+lhi = c*5+kh (g=15 pad), j=kw (5..7 pad)
        const int e = ent - 88;
        const int s = e >> 1; hl = e & 1;
        const int g  = s * 4 + lhi;
        const int gc = g > 14 ? 14 : g;
        const int c  = (gc * 52) >> 8;   // gc/5
        const int kh = gc - 5 * c;
#pragma unroll
        for (int j = 0; j < 8; j++)
            w[j] = (g < 15 && o < 8 && j < 5) ? K1[(c * 25 + kh * 5 + j) * 8 + o] : 0.f;
    }
    short8 v;
#pragma unroll
    for (int j = 0; j < 8; j++) {
        const u16 h = f2bf(w[j]);
        v[j] = hl ? (short)f2bf(w[j] - bf2f(h)) : (short)h;
    }
    W[slot] = v;
}

// ============ conv helpers (half-channel-plane LDS layout, 15x15 pad) ============
// 16-ch tensor @ base (shorts): hi half0 [0,1800), hi half1 [1800,3600),
//                               lo half0 [3600,5400), lo half1 [5400,7200)
// row stride 15 px, pixel stride 8 shorts = 16 B. Plane stride 1800 shorts is
// bank-proven (r15: 1680-short stride raised conflicts 17.6M->26.2M).
// 4-wave dispatch: m0=(wave+rot)&3 -> tiles m0, m0+4 (and 8 when m0==0).
// SINGLE accumulator: dual-acc pushed VGPR 48->68 over the 64 cliff (r13);
// dual-tile interleave also regressed (r17). setprio null (r16).

__device__ __forceinline__ void conv8(const u16* __restrict__ s0,   // 8-ch src: hi [0,1800), lo +3600
                                      u16* __restrict__ d0,
                                      const short8* __restrict__ Wt,
                                      int wave, int lane, int rot)
{
    const int o   = lane & 15;
    const int lhi = lane >> 4;
    short8 Bhi[3], Blo[3];
#pragma unroll
    for (int s = 0; s < 3; s++) {
        Bhi[s] = Wt[(s * 2 + 0) * 64 + lane];
        Blo[s] = Wt[(s * 2 + 1) * 64 + lane];
    }
    const u16* sl = s0 + 3600;
    const int r0 = lane & 15;

    auto tile = [&](int m) {
        const int p  = m * 16 + r0;
        const int ip = (p * 683) >> 13;          // p/12
        const int jp = p - 12 * ip;
        f32x4 acc = {0.f, 0.f, 0.f, 0.f};
#pragma unroll
        for (int s = 0; s < 3; s++) {
            const int t  = s * 4 + lhi;
            const int tt = t > 8 ? 8 : t;
            const int kh = (tt * 11) >> 5;       // tt/3
            const int kw = tt - 3 * kh;
            const int px = (ip + kh) * 15 + (jp + kw);
            const short8 Ahi = *(const short8*)(s0 + px * 8);
            const short8 Alo = *(const short8*)(sl + px * 8);
            acc = MFMA(Ahi, Bhi[s], acc);
            acc = MFMA(Alo, Bhi[s], acc);
            acc = MFMA(Ahi, Blo[s], acc);
        }
        const int p0 = m * 16 + lhi * 4;
#pragma unroll
        for (int r = 0; r < 4; r++) {
            const int pp = p0 + r;
            const int ii = (pp * 683) >> 13;
            const int jj = pp - 12 * ii;
            const float v = fmaxf(acc[r], 0.f);
            const u16 h = f2bf_hw(v);
            const int px2 = (ii + 1) * 15 + (jj + 1);
            const int da  = (o >> 3) * 1800 + px2 * 8 + (o & 7);
            d0[da]        = h;
            d0[da + 3600] = f2bf_hw(v - bf2f(h));
        }
    };
    const int m0 = (wave + rot) & 3;
    tile(m0);
    tile(m0 + 4);
    if (m0 == 0) tile(8);
}

__device__ __forceinline__ void conv16(const u16* __restrict__ s0,
                                       u16* __restrict__ d0,
                                       const short8* __restrict__ Wt,
                                       int wave, int lane, int rot)
{
    const int o    = lane & 15;
    const int lhi  = lane >> 4;
    const int hsel = lhi & 1;
    const int tsel = lhi >> 1;
    short8 Bhi[5], Blo[5];
#pragma unroll
    for (int s = 0; s < 5; s++) {
        Bhi[s] = Wt[(s * 2 + 0) * 64 + lane];
        Blo[s] = Wt[(s * 2 + 1) * 64 + lane];
    }
    const u16* sh = s0 + hsel * 1800;
    const u16* sl = sh + 3600;
    const int r0 = lane & 15;

    auto tile = [&](int m) {
        const int p  = m * 16 + r0;
        const int ip = (p * 683) >> 13;
        const int jp = p - 12 * ip;
        f32x4 acc = {0.f, 0.f, 0.f, 0.f};
#pragma unroll
        for (int s = 0; s < 5; s++) {
            const int t  = 2 * s + tsel;
            const int tt = t > 8 ? 8 : t;
            const int kh = (tt * 11) >> 5;
            const int kw = tt - 3 * kh;
            const int px = (ip + kh) * 15 + (jp + kw);
            const short8 Ahi = *(const short8*)(sh + px * 8);
            const short8 Alo = *(const short8*)(sl + px * 8);
            acc = MFMA(Ahi, Bhi[s], acc);
            acc = MFMA(Alo, Bhi[s], acc);
            acc = MFMA(Ahi, Blo[s], acc);
        }
        const int p0 = m * 16 + lhi * 4;
#pragma unroll
        for (int r = 0; r < 4; r++) {
            const int pp = p0 + r;
            const int ii = (pp * 683) >> 13;
            const int jj = pp - 12 * ii;
            const float v = fmaxf(acc[r], 0.f);
            const u16 h = f2bf_hw(v);
            const int px2 = (ii + 1) * 15 + (jj + 1);
            const int da  = (o >> 3) * 1800 + px2 * 8 + (o & 7);
            d0[da]        = h;
            d0[da + 3600] = f2bf_hw(v - bf2f(h));
        }
    };
    const int m0 = (wave + rot) & 3;
    tile(m0);
    tile(m0 + 4);
    if (m0 == 0) tile(8);
}

// ============ main fused kernel ============
// CHAMPION STRUCTURE (r14, 203.9 us): TPB=256, single-acc, 15x15 planes,
// 29184 B LDS -> 5 blocks/CU, VGPR 48, in-phase zeros, absmax 0.0.
// Hard-won constraints: min-waves launch_bounds pins spill (r3/r8); VGPR>64
// halves occupancy (r13); TPB!=256 loses (r8/r9/r12); plane stride 1800 is
// bank-optimal (r11/r15); setprio null (r16); dual-chain ILP loses (r13/r17).
// Binding resource: LDS pipe (~10 b128 reads + 8 u16 writes per tile,
// ~145-160 us serialized) -- not MFMA (20%), not HBM (2%).
extern "C" __global__ void __launch_bounds__(TPB)
cnn_fused(const float* __restrict__ xg,
          const float* __restrict__ Wfc, const float* __restrict__ bfc,
          const short8* __restrict__ W, float* __restrict__ out)
{
    // byte map:
    //  A [0,14400)      : 16-ch tensor (4 planes of 1800 shorts)
    //  B [14400,28800)  : image bf16 [3][30][32] hi/lo first; then 16-ch tensor;
    //                     finally sF f32[1152]. Ring re-zeroed inside L2 phase.
    //  sLog [28800,28864)
    __shared__ __align__(16) unsigned char smem[28864];
    u16*   const Ah   = (u16*)smem;
    u16*   const Bh   = (u16*)(smem + 14400);
    u16*   const Sh   = (u16*)(smem + 14400);    // image: hi 2880 shorts, lo +2880
    float* const sF   = (float*)(smem + 14400);
    float* const sLog = (float*)(smem + 28800);
    uint4* const z4   = (uint4*)smem;
    const uint4 Z = {0u, 0u, 0u, 0u};

    const int tid  = threadIdx.x;
    const int lane = tid & 63;
    const int wave = tid >> 6;
    const int img  = blockIdx.x;

    // full clear (1804 x 16B): A's pad rings + image pad ring stay zero
    for (int i = tid; i < 1804; i += TPB) z4[i] = Z;
    __syncthreads();

    // stage image as bf16 hi/lo planar [3][30][32] into B, interior rows/cols 1..28
    const float4* xi4 = (const float4*)(xg + (size_t)img * 2352);
    for (int i4 = tid; i4 < 588; i4 += TPB) {
        const float4 v = xi4[i4];
        const int c = i4 / 196;
        const int rem = i4 - c * 196;
        const int r = rem / 7;
        const int q = rem - r * 7;
        const int ad = c * 960 + (r + 1) * 32 + q * 4 + 1;
        const float vv[4] = {v.x, v.y, v.z, v.w};
#pragma unroll
        for (int e = 0; e < 4; e++) {
            const u16 h = f2bf_hw(vv[e]);
            Sh[ad + e]        = h;
            Sh[ad + e + 2880] = f2bf_hw(vv[e] - bf2f(h));
        }
    }
    __syncthreads();

    // ---- L1: 5x5 s2 p1, 3->8, 13x13 full, ReLU. MFMA split bf16. B(img) -> A(8ch)
    {
        const short8* Wt1 = W + 5632;            // ent 88
        const int o   = lane & 15;
        const int lhi = lane >> 4;
        short8 B1h[4], B1l[4];
#pragma unroll
        for (int s = 0; s < 4; s++) {
            B1h[s] = Wt1[(s * 2 + 0) * 64 + lane];
            B1l[s] = Wt1[(s * 2 + 1) * 64 + lane];
        }
        const u16* slo = Sh + 2880;
        for (int m = wave; m < 11; m += 4) {
            const int p  = m * 16 + o;
            const int pc = p > 168 ? 168 : p;
            const int i = (pc * 316) >> 12;      // pc/13
            const int j = pc - 13 * i;
            f32x4 acc = {0.f, 0.f, 0.f, 0.f};
#pragma unroll
            for (int s = 0; s < 4; s++) {
                const int g  = s * 4 + lhi;
                const int gc = g > 14 ? 14 : g;
                const int c  = (gc * 52) >> 8;   // gc/5
                const int kh = gc - 5 * c;
                const int ad = c * 960 + (2 * i + kh) * 32 + 2 * j;
                const short8 Ahi = *(const short8*)(Sh + ad);
                const short8 Alo = *(const short8*)(slo + ad);
                acc = MFMA(Ahi, B1h[s], acc);
                acc = MFMA(Alo, B1h[s], acc);
                acc = MFMA(Ahi, B1l[s], acc);
            }
#pragma unroll
            for (int r = 0; r < 4; r++) {
                const int pp = m * 16 + lhi * 4 + r;
                if (pp < 169 && o < 8) {
                    const int ii = (pp * 316) >> 12;
                    const int jj = pp - 13 * ii;
                    const float v = fmaxf(acc[r], 0.f);
                    const u16 h = f2bf_hw(v);
                    const int da = ((ii + 1) * 15 + (jj + 1)) * 8 + o;
                    Ah[da]        = h;
                    Ah[da + 3600] = f2bf_hw(v - bf2f(h));
                }
            }
        }
    }
    __syncthreads();

    // ---- L2 phase: conv8 A8 -> B16, plus B read-extent ring zero (rows/cols
    // 0 and 13 of each plane; stale image bytes live there). Ring is disjoint
    // from L2's interior writes; L2 reads only A -> race-free in-phase.
    conv8(Ah, Bh, W, wave, lane, 0);
    if (tid < 208) {
        const int pl = tid / 52, e = tid - pl * 52;
        const int px = (e < 14) ? e
                     : (e < 28) ? 195 + (e - 14)
                     : (e < 40) ? (e - 27) * 15
                                : (e - 39) * 15 + 13;
        z4[900 + pl * 225 + px] = Z;
    }
    __syncthreads();

    // ---- L3 phase: conv16 B -> A, plus strip-zero of A px row/col 13 (holds
    // stale L1 row/col 12; reference has L3's truncated zeros there). Disjoint
    // from L3's interior writes; L3 reads only B. (r11/r14: absmax -> 0.0)
    conv16(Bh, Ah, W + 384, wave, lane, 1);
    if (tid < 108) {
        const int pl = tid / 27, e = tid - pl * 27;
        const int px = (e < 14) ? 195 + e : (e - 14) * 15 + 13;
        z4[pl * 225 + px] = Z;
    }
    __syncthreads();

    conv16(Ah, Bh, W + 1024, wave, lane, 2);       // L4: A -> B (B px13 ring still zero)
    __syncthreads();
    conv16(Bh, Ah, W + 1664, wave, lane, 3);       // L5: B -> A (A px13 strip still zero)
    __syncthreads();

    // ---- L6 phase: conv A -> sF [32][6][6] planar, plus zero of sF's
    // complement slots (row 5 + col 5 of each 6x6 map, 11 slots x 32 ch).
    // Complement is disjoint from L6's interior writes; L6 reads only A.
    for (int i = tid; i < 352; i += TPB) {
        const int o = i / 11, k = i - o * 11;
        const int slot = (k < 6) ? o * 36 + 30 + k : o * 36 + (k - 6) * 6 + 5;
        sF[slot] = 0.f;
    }
    if (wave < 4) {
        const short8* Wt6 = W + 2304;
        const int mt   = wave >> 1;
        const int nh   = wave & 1;
        const int lhi  = lane >> 4;
        const int hsel = lhi & 1;
        const int tsel = lhi >> 1;
        const int o    = nh * 16 + (lane & 15);
        const int pr = mt * 16 + (lane & 15);
        const int pe = pr < 25 ? pr : 0;
        const int ia = (pe * 52) >> 8;            // pe/5
        const int ja = pe - 5 * ia;
        const u16* sh = Ah + hsel * 1800;
        const u16* sl = sh + 3600;
        f32x4 acc = {0.f, 0.f, 0.f, 0.f};
#pragma unroll 4
        for (int s = 0; s < 13; s++) {
            const int t  = 2 * s + tsel;
            const int tt = t > 24 ? 24 : t;
            const int kh = (tt * 52) >> 8;        // tt/5
            const int kw = tt - 5 * kh;
            const int px = (2 * ia + kh) * 15 + (2 * ja + kw);
            const short8 Ahi = *(const short8*)(sh + px * 8);
            const short8 Alo = *(const short8*)(sl + px * 8);
            const short8 Bh2 = Wt6[((s * 2 + 0) * 2 + nh) * 64 + lane];
            const short8 Bl2 = Wt6[((s * 2 + 1) * 2 + nh) * 64 + lane];
            acc = MFMA(Ahi, Bh2, acc);
            acc = MFMA(Alo, Bh2, acc);
            acc = MFMA(Ahi, Bl2, acc);
        }
        const int p0 = mt * 16 + lhi * 4;
#pragma unroll
        for (int r = 0; r < 4; r++) {
            const int pp = p0 + r;
            if (pp < 25) {
                const int ii = (pp * 52) >> 8;
                const int jj = pp - 5 * ii;
                sF[o * 36 + ii * 6 + jj] = acc[r];
            }
        }
    }
    __syncthreads();

    // ---- FC: logits[c] = sF . Wfc[c] + bfc[c]
    if (tid < 160) {
        const int c = tid >> 4;
        const int l = tid & 15;
        const float4* fv = (const float4*)(sF + l * 72);
        const float4* wv = (const float4*)(Wfc + c * 1152 + l * 72);
        float p = 0.f;
#pragma unroll
        for (int m = 0; m < 18; m++) {
            const float4 a = fv[m];
            const float4 b = wv[m];
            p = fmaf(a.x, b.x, p);
            p = fmaf(a.y, b.y, p);
            p = fmaf(a.z, b.z, p);
            p = fmaf(a.w, b.w, p);
        }
        p += __shfl_down(p, 8, 16);
        p += __shfl_down(p, 4, 16);
        p += __shfl_down(p, 2, 16);
        p += __shfl_down(p, 1, 16);
        if (l == 0) sLog[c] = p + bfc[c];
    }
    __syncthreads();

    // ---- softmax
    if (tid < 10) {
        float mx = sLog[0];
#pragma unroll
        for (int k = 1; k < 10; k++) mx = fmaxf(mx, sLog[k]);
        float s = 0.f;
#pragma unroll
        for (int k = 0; k < 10; k++) s += expf(sLog[k] - mx);
        out[(size_t)img * 10 + tid] = expf(sLog[tid] - mx) / s;
    }
}

extern "C" void kernel_launch(void* const* d_in, const int* in_sizes, int n_in,
                              void* d_out, int out_size, void* d_ws, size_t ws_size,
                              hipStream_t stream) {
    const float* x   = (const float*)d_in[0];
    const float* K1  = (const float*)d_in[1];
    const float* K2  = (const float*)d_in[2];
    const float* K3  = (const float*)d_in[3];
    const float* K4  = (const float*)d_in[4];
    const float* K5  = (const float*)d_in[5];
    const float* K6  = (const float*)d_in[6];
    const float* Wfc = (const float*)d_in[7];
    const float* bfc = (const float*)d_in[8];
    float* out = (float*)d_out;
    short8* W = (short8*)d_ws;

    prep_w<<<24, 256, 0, stream>>>(K1, K2, K3, K4, K5, K6, W);

    const int B = in_sizes[0] / 2352;   // 8192
    cnn_fused<<<B, TPB, 0, stream>>>(x, Wfc, bfc, W, out);
}